// Round 2
// baseline (15.817 us; speedup 1.0000x reference)
//
#include <hip/hip_runtime.h>
#include <hip/hip_bf16.h>

// Reference: out[b,i,d] = v[b,i,d] * sum_j softmax(scores)[b,i,j]  == v[b,i,d]
// (softmax row-sum is exactly 1 up to fp32 rounding ~1e-5 << threshold 0.104).
// Optimal kernel = copy v -> out. Replace the SDMA hipMemcpyAsync (4.45 TB/s
// measured) with a float4 grid-stride compute-core copy (~6.3 TB/s achievable).

__global__ __launch_bounds__(256) void copy_v_kernel(const float4* __restrict__ src,
                                                     float4* __restrict__ dst,
                                                     int n4) {
    int stride = gridDim.x * blockDim.x;
    for (int i = blockIdx.x * blockDim.x + threadIdx.x; i < n4; i += stride) {
        dst[i] = src[i];
    }
}

extern "C" void kernel_launch(void* const* d_in, const int* in_sizes, int n_in,
                              void* d_out, int out_size, void* d_ws, size_t ws_size,
                              hipStream_t stream) {
    const float4* v = (const float4*)d_in[2];   // inputs: q, k, v
    float4* out = (float4*)d_out;
    (void)in_sizes; (void)n_in; (void)d_ws; (void)ws_size;
    int n4 = out_size / 4;                      // 8*2048*512 / 4 = 2,097,152
    int block = 256;
    int grid = 2048;                            // 8 blocks/CU, grid-stride covers rest
    copy_v_kernel<<<grid, block, 0, stream>>>(v, out, n4);
}

// Round 4
// 14.480 us; speedup vs baseline: 1.0923x; 1.0923x over previous
//
#include <hip/hip_runtime.h>
#include <hip/hip_bf16.h>

// Reference: out[b,i,d] = v[b,i,d] * sum_j softmax(scores)[b,i,j]  == v[b,i,d]
// (softmax row-sum is exactly 1 up to fp32 rounding ~1e-5 << threshold 0.104).
// Optimal kernel = copy v -> out (67.1 MB HBM traffic, roofline ~10.7 us at
// 6.3 TB/s). Exact-fit launch (1 float4/thread, 32 blocks/CU) + non-temporal
// load/store (skip L2 allocation for streaming data). Use a native clang
// ext_vector_type — __builtin_nontemporal_* rejects HIP_vector_type wrappers.

typedef float f32x4 __attribute__((ext_vector_type(4)));

__global__ __launch_bounds__(256) void copy_v_nt_kernel(const f32x4* __restrict__ src,
                                                        f32x4* __restrict__ dst) {
    int i = blockIdx.x * 256 + threadIdx.x;
    f32x4 val = __builtin_nontemporal_load(&src[i]);
    __builtin_nontemporal_store(val, &dst[i]);
}

extern "C" void kernel_launch(void* const* d_in, const int* in_sizes, int n_in,
                              void* d_out, int out_size, void* d_ws, size_t ws_size,
                              hipStream_t stream) {
    const f32x4* v = (const f32x4*)d_in[2];     // inputs: q, k, v
    f32x4* out = (f32x4*)d_out;
    (void)in_sizes; (void)n_in; (void)d_ws; (void)ws_size;
    int n4 = out_size / 4;                      // 8*2048*512/4 = 2,097,152 (mult of 256)
    int grid = n4 / 256;                        // 8192 blocks, exact fit
    copy_v_nt_kernel<<<grid, 256, 0, stream>>>(v, out);
}